// Round 3
// baseline (438.622 us; speedup 1.0000x reference)
//
#include <hip/hip_runtime.h>

// Problem constants
#define TT 8
#define WQ 75
#define CC 64
#define HW 441
#define WAY 5
#define SHOT 5
#define NSAMP 2205     // SHOT*HW
#define NEG 0.2f

// ws layout (floats):
//   Wfinal : 40  * 4096            = 163840
//   pG     : 200 * 4096            = 819200
//   pS     : 200 * 64              = 12800
// total = 995840 floats = 3.98 MB

// ---------------------------------------------------------------------------
// Kernel 1: per-(t,shot-slot) partial second moment G = X X^T and column sums.
// X is [64][441] contiguous. 200 blocks (t*25+s), 256 threads.
// ---------------------------------------------------------------------------
__global__ __launch_bounds__(256) void k_partial(const float* __restrict__ sup,
                                                 float* __restrict__ pG,
                                                 float* __restrict__ pS) {
    const int b = blockIdx.x;                    // t*25 + s
    const float* __restrict__ X = sup + (size_t)b * CC * HW;
    __shared__ float lds[32 * 68];               // [pp][c], stride 68 words
    const int tid = threadIdx.x;
    const int i = tid & 15;                      // c-tile index
    const int j = tid >> 4;                      // d-tile index

    float acc[4][4];
#pragma unroll
    for (int a = 0; a < 4; ++a)
#pragma unroll
        for (int bb = 0; bb < 4; ++bb) acc[a][bb] = 0.f;
    float cs = 0.f;                              // column sum for c==tid (tid<64)

    for (int chunk = 0; chunk < 14; ++chunk) {
        const int p0 = chunk * 32;
        __syncthreads();
        // stage 64 rows x 32 positions, transposed into [pp][c]
#pragma unroll
        for (int k = 0; k < 8; ++k) {
            const int e = tid + k * 256;         // 0..2047
            const int r = e >> 5;                // channel 0..63
            const int pp = e & 31;               // position within chunk
            const int p = p0 + pp;
            const float v = (p < HW) ? X[r * HW + p] : 0.f;
            lds[pp * 68 + r] = v;
        }
        __syncthreads();
#pragma unroll 4
        for (int pp = 0; pp < 32; ++pp) {
            const float* row = &lds[pp * 68];
            const float a0 = row[4 * i + 0], a1 = row[4 * i + 1],
                        a2 = row[4 * i + 2], a3 = row[4 * i + 3];
            const float b0 = row[4 * j + 0], b1 = row[4 * j + 1],
                        b2 = row[4 * j + 2], b3 = row[4 * j + 3];
            acc[0][0] += a0 * b0; acc[0][1] += a0 * b1; acc[0][2] += a0 * b2; acc[0][3] += a0 * b3;
            acc[1][0] += a1 * b0; acc[1][1] += a1 * b1; acc[1][2] += a1 * b2; acc[1][3] += a1 * b3;
            acc[2][0] += a2 * b0; acc[2][1] += a2 * b1; acc[2][2] += a2 * b2; acc[2][3] += a2 * b3;
            acc[3][0] += a3 * b0; acc[3][1] += a3 * b1; acc[3][2] += a3 * b2; acc[3][3] += a3 * b3;
        }
        if (tid < CC) {
#pragma unroll 8
            for (int pp = 0; pp < 32; ++pp) cs += lds[pp * 68 + tid];
        }
    }

    float* __restrict__ G = pG + (size_t)b * 4096;
#pragma unroll
    for (int a = 0; a < 4; ++a)
#pragma unroll
        for (int bb = 0; bb < 4; ++bb)
            G[(4 * i + a) * 64 + (4 * j + bb)] = acc[a][bb];
    if (tid < CC) pS[b * 64 + tid] = cs;
}

// ---------------------------------------------------------------------------
// Kernel 1b: reduce 5 shots -> covariance -> W (upper-tri, off-diag doubled,
// zeros below diagonal). 40 blocks (t*5+way), 256 threads.
// ---------------------------------------------------------------------------
__global__ __launch_bounds__(256) void k_finalize(const float* __restrict__ pG,
                                                  const float* __restrict__ pS,
                                                  float* __restrict__ W) {
    const int b = blockIdx.x;                    // t*5 + way
    const int t = b / WAY, way = b % WAY;
    const int s0 = t * 25 + way * SHOT;
    float* __restrict__ Wm = W + (size_t)b * 4096;

    for (int idx = threadIdx.x; idx < 4096; idx += 256) {
        const int c = idx >> 6, d = idx & 63;
        if (d < c) continue;                     // owner of pair (c,d) writes both
        float g = 0.f, Sc = 0.f, Sd = 0.f;
#pragma unroll
        for (int s = 0; s < SHOT; ++s) {
            g  += pG[(size_t)(s0 + s) * 4096 + idx];
            Sc += pS[(s0 + s) * 64 + c];
            Sd += pS[(s0 + s) * 64 + d];
        }
        const float cov = (g - Sc * Sd * (1.f / NSAMP)) * (1.f / (HW - 1));
        if (d == c) {
            Wm[idx] = cov;
        } else {
            Wm[c * 64 + d] = 2.f * cov;
            Wm[d * 64 + c] = 0.f;
        }
    }
}

// ---------------------------------------------------------------------------
// Kernel 2: per-(t,q) block. One thread per spatial position (448 thr, 7 waves).
// q column lives in 64 VGPRs; W read with thread-uniform addresses (s_load).
// sim_p = sum_c q_c * (sum_{d>=c} W[c][d] q_d), then lrelu + conv_w reduce.
// ---------------------------------------------------------------------------
__global__ __launch_bounds__(448) void k_sim(const float* __restrict__ Q,
                                             const float* __restrict__ W,
                                             const float* __restrict__ cw,
                                             const float* __restrict__ cb,
                                             float* __restrict__ out) {
    const int b = blockIdx.x;                    // t*75 + qi
    const int t = b / WQ;
    const int tid = threadIdx.x;
    const int lane = tid & 63;
    const int wave = tid >> 6;                   // 0..6
    const int p = tid;
    const float validf = (p < HW) ? 1.f : 0.f;
    const int pc = (p < HW) ? p : (HW - 1);

    const float* __restrict__ Qb = Q + (size_t)b * CC * HW;

    float q[CC];
#pragma unroll
    for (int c = 0; c < CC; ++c) q[c] = Qb[c * HW + pc] * validf;

    __shared__ float red[CC * 9];
    __shared__ float mu[CC];
    __shared__ float fin[8];

    // block-wide per-channel mean over 441 valid positions
#pragma unroll
    for (int c = 0; c < CC; ++c) {
        float v = q[c];
#pragma unroll
        for (int m = 32; m > 0; m >>= 1) v += __shfl_xor(v, m, 64);
        if (lane == 0) red[c * 9 + wave] = v;
    }
    __syncthreads();
    if (tid < CC) {
        float s = 0.f;
#pragma unroll
        for (int w2 = 0; w2 < 7; ++w2) s += red[tid * 9 + w2];
        mu[tid] = s * (1.f / HW);
    }
    __syncthreads();
#pragma unroll
    for (int c = 0; c < CC; ++c) q[c] -= mu[c];

    const float cwp = cw[pc] * validf;

    for (int w = 0; w < WAY; ++w) {
        const float* __restrict__ Wm = W + (size_t)(t * WAY + w) * 4096;
        float sim = 0.f;
#pragma unroll
        for (int c = 0; c < CC; ++c) {
            const float* __restrict__ row = Wm + c * 64;
            float t0 = 0.f, t1 = 0.f, t2 = 0.f, t3 = 0.f;
            const int dstart = c & ~3;           // aligned start; W below diag is 0
#pragma unroll
            for (int d = dstart; d < CC; d += 4) {
                t0 += row[d + 0] * q[d + 0];
                t1 += row[d + 1] * q[d + 1];
                t2 += row[d + 2] * q[d + 2];
                t3 += row[d + 3] * q[d + 3];
            }
            sim += q[c] * ((t0 + t1) + (t2 + t3));
        }
        // LeakyReLU then weighted reduction with conv_w
        const float x = (sim >= 0.f) ? sim : NEG * sim;
        float contrib = x * cwp;
#pragma unroll
        for (int m = 32; m > 0; m >>= 1) contrib += __shfl_xor(contrib, m, 64);
        if (lane == 0) fin[wave] = contrib;
        __syncthreads();
        if (tid == 0) {
            float s = 0.f;
#pragma unroll
            for (int w2 = 0; w2 < 7; ++w2) s += fin[w2];
            out[b * WAY + w] = s + cb[0];
        }
        __syncthreads();
    }
}

// ---------------------------------------------------------------------------
extern "C" void kernel_launch(void* const* d_in, const int* in_sizes, int n_in,
                              void* d_out, int out_size, void* d_ws, size_t ws_size,
                              hipStream_t stream) {
    const float* q   = (const float*)d_in[0];   // (8,75,64,21,21)
    const float* sup = (const float*)d_in[1];   // (8,25,64,21,21)
    const float* cw  = (const float*)d_in[2];   // (441,)
    const float* cb  = (const float*)d_in[3];   // (1,)
    float* out = (float*)d_out;                  // (8,75,5)

    float* wsf  = (float*)d_ws;
    float* Wbuf = wsf;                           // 163840 floats
    float* pG   = wsf + 163840;                  // 819200 floats
    float* pS   = wsf + 163840 + 819200;         // 12800 floats

    k_partial<<<TT * 25, 256, 0, stream>>>(sup, pG, pS);
    k_finalize<<<TT * WAY, 256, 0, stream>>>(pG, pS, Wbuf);
    k_sim<<<TT * WQ, 448, 0, stream>>>(q, Wbuf, cw, cb, out);
}

// Round 4
// 392.908 us; speedup vs baseline: 1.1163x; 1.1163x over previous
//
#include <hip/hip_runtime.h>

// Problem constants
#define TT 8
#define WQ 75
#define CC 64
#define HW 441
#define WAY 5
#define SHOT 5
#define NSAMP 2205     // SHOT*HW
#define NEG 0.2f

// ws layout (floats):
//   Wfinal : 40  * 4096            = 163840
//   pG     : 200 * 4096            = 819200
//   pS     : 200 * 64              = 12800
// total = 995840 floats = 3.98 MB

// ---------------------------------------------------------------------------
// Kernel 1: per-(t,shot-slot) partial second moment G = X X^T and column sums.
// X is [64][441] contiguous. 200 blocks (t*25+s), 256 threads.
// Register double-buffer: issue next chunk's global loads before computing
// current chunk so HBM latency hides under the outer-product FMAs.
// ---------------------------------------------------------------------------
__global__ __launch_bounds__(256) void k_partial(const float* __restrict__ sup,
                                                 float* __restrict__ pG,
                                                 float* __restrict__ pS) {
    const int b = blockIdx.x;                    // t*25 + s
    const float* __restrict__ X = sup + (size_t)b * CC * HW;
    __shared__ float lds[32 * 68];               // [pp][c], stride 68 words
    const int tid = threadIdx.x;
    const int i = tid & 15;                      // c-tile index
    const int j = tid >> 4;                      // d-tile index

    float acc[4][4];
#pragma unroll
    for (int a = 0; a < 4; ++a)
#pragma unroll
        for (int bb = 0; bb < 4; ++bb) acc[a][bb] = 0.f;
    float cs = 0.f;                              // column sum for c==tid (tid<64)

    float ld[8];
    // prologue: load chunk 0
#pragma unroll
    for (int k = 0; k < 8; ++k) {
        const int e = tid + k * 256;
        const int r = e >> 5, pp = e & 31;
        const int p = pp;                        // chunk 0
        ld[k] = (p < HW) ? X[r * HW + p] : 0.f;
    }

    for (int chunk = 0; chunk < 14; ++chunk) {
        __syncthreads();                         // LDS free from previous compute
#pragma unroll
        for (int k = 0; k < 8; ++k) {
            const int e = tid + k * 256;
            const int r = e >> 5, pp = e & 31;
            lds[pp * 68 + r] = ld[k];
        }
        // prefetch next chunk while this one is being consumed
        float ld2[8];
        if (chunk < 13) {
            const int p0 = (chunk + 1) * 32;
#pragma unroll
            for (int k = 0; k < 8; ++k) {
                const int e = tid + k * 256;
                const int r = e >> 5, pp = e & 31;
                const int p = p0 + pp;
                ld2[k] = (p < HW) ? X[r * HW + p] : 0.f;
            }
        } else {
#pragma unroll
            for (int k = 0; k < 8; ++k) ld2[k] = 0.f;
        }
        __syncthreads();
#pragma unroll 4
        for (int pp = 0; pp < 32; ++pp) {
            const float* row = &lds[pp * 68];
            const float a0 = row[4 * i + 0], a1 = row[4 * i + 1],
                        a2 = row[4 * i + 2], a3 = row[4 * i + 3];
            const float b0 = row[4 * j + 0], b1 = row[4 * j + 1],
                        b2 = row[4 * j + 2], b3 = row[4 * j + 3];
            acc[0][0] += a0 * b0; acc[0][1] += a0 * b1; acc[0][2] += a0 * b2; acc[0][3] += a0 * b3;
            acc[1][0] += a1 * b0; acc[1][1] += a1 * b1; acc[1][2] += a1 * b2; acc[1][3] += a1 * b3;
            acc[2][0] += a2 * b0; acc[2][1] += a2 * b1; acc[2][2] += a2 * b2; acc[2][3] += a2 * b3;
            acc[3][0] += a3 * b0; acc[3][1] += a3 * b1; acc[3][2] += a3 * b2; acc[3][3] += a3 * b3;
        }
        if (tid < CC) {
#pragma unroll 8
            for (int pp = 0; pp < 32; ++pp) cs += lds[pp * 68 + tid];
        }
#pragma unroll
        for (int k = 0; k < 8; ++k) ld[k] = ld2[k];
    }

    float* __restrict__ G = pG + (size_t)b * 4096;
#pragma unroll
    for (int a = 0; a < 4; ++a)
#pragma unroll
        for (int bb = 0; bb < 4; ++bb)
            G[(4 * i + a) * 64 + (4 * j + bb)] = acc[a][bb];
    if (tid < CC) pS[b * 64 + tid] = cs;
}

// ---------------------------------------------------------------------------
// Kernel 1b: reduce 5 shots -> covariance -> W (upper-tri, off-diag doubled,
// zeros below diagonal). 40 blocks (t*5+way), 256 threads.
// ---------------------------------------------------------------------------
__global__ __launch_bounds__(256) void k_finalize(const float* __restrict__ pG,
                                                  const float* __restrict__ pS,
                                                  float* __restrict__ W) {
    const int b = blockIdx.x;                    // t*5 + way
    const int t = b / WAY, way = b % WAY;
    const int s0 = t * 25 + way * SHOT;
    float* __restrict__ Wm = W + (size_t)b * 4096;

    for (int idx = threadIdx.x; idx < 4096; idx += 256) {
        const int c = idx >> 6, d = idx & 63;
        if (d < c) continue;                     // owner of pair (c,d) writes both
        float g = 0.f, Sc = 0.f, Sd = 0.f;
#pragma unroll
        for (int s = 0; s < SHOT; ++s) {
            g  += pG[(size_t)(s0 + s) * 4096 + idx];
            Sc += pS[(s0 + s) * 64 + c];
            Sd += pS[(s0 + s) * 64 + d];
        }
        const float cov = (g - Sc * Sd * (1.f / NSAMP)) * (1.f / (HW - 1));
        if (d == c) {
            Wm[idx] = cov;
        } else {
            Wm[c * 64 + d] = 2.f * cov;
            Wm[d * 64 + c] = 0.f;
        }
    }
}

// ---------------------------------------------------------------------------
// Kernel 2 v3: one (t,q,way) per block; 448 threads, thread = position.
// q[64] centered then PINNED in VGPRs via empty inline-asm (defeats LLVM's
// rematerialize-from-global heuristic that made v2 L2-BW-bound).
// Inner loop: s_load W row (wave-uniform) + v_fmac only.
// ---------------------------------------------------------------------------
__global__ __launch_bounds__(448) void k_sim(const float* __restrict__ Q,
                                             const float* __restrict__ W,
                                             const float* __restrict__ cw,
                                             const float* __restrict__ cb,
                                             float* __restrict__ out) {
    const int b = blockIdx.x;                    // (t*75+q)*5 + w
    const int w = b % WAY;
    const int tq = b / WAY;                      // t*75 + q
    const int t = tq / WQ;
    const int tid = threadIdx.x;
    const int lane = tid & 63;
    const int wave = tid >> 6;                   // 0..6
    const int p = tid;
    const float validf = (p < HW) ? 1.f : 0.f;
    const int pc = (p < HW) ? p : (HW - 1);

    const float* __restrict__ Qb = Q + (size_t)tq * CC * HW;

    float q[CC];
#pragma unroll
    for (int c = 0; c < CC; ++c) q[c] = Qb[c * HW + pc] * validf;

    __shared__ float red[CC * 9];
    __shared__ float mu[CC];
    __shared__ float fin[8];

    // block-wide per-channel mean over 441 valid positions
#pragma unroll
    for (int c = 0; c < CC; ++c) {
        float v = q[c];
#pragma unroll
        for (int m = 32; m > 0; m >>= 1) v += __shfl_xor(v, m, 64);
        if (lane == 0) red[c * 9 + wave] = v;
    }
    __syncthreads();
    if (tid < CC) {
        float s = 0.f;
#pragma unroll
        for (int w2 = 0; w2 < 7; ++w2) s += red[tid * 9 + w2];
        mu[tid] = s * (1.f / HW);
    }
    __syncthreads();
#pragma unroll
    for (int c = 0; c < CC; ++c) {
        q[c] -= mu[c];
        asm volatile("" : "+v"(q[c]));           // pin: no remat, no reload
    }

    const float cwp = cw[pc] * validf;
    const float* __restrict__ Wm = W + (size_t)(t * WAY + w) * 4096;

    float sim = 0.f;
#pragma unroll
    for (int c = 0; c < CC; ++c) {
        const float* __restrict__ row = Wm + c * 64;
        float t0 = 0.f, t1 = 0.f, t2 = 0.f, t3 = 0.f;
        const int dstart = c & ~3;               // aligned start; W below diag is 0
#pragma unroll
        for (int d = dstart; d < CC; d += 4) {
            t0 += row[d + 0] * q[d + 0];
            t1 += row[d + 1] * q[d + 1];
            t2 += row[d + 2] * q[d + 2];
            t3 += row[d + 3] * q[d + 3];
        }
        sim += q[c] * ((t0 + t1) + (t2 + t3));
    }

    // LeakyReLU then weighted reduction with conv_w
    const float x = (sim >= 0.f) ? sim : NEG * sim;
    float contrib = x * cwp;
#pragma unroll
    for (int m = 32; m > 0; m >>= 1) contrib += __shfl_xor(contrib, m, 64);
    if (lane == 0) fin[wave] = contrib;
    __syncthreads();
    if (tid == 0) {
        float s = 0.f;
#pragma unroll
        for (int w2 = 0; w2 < 7; ++w2) s += fin[w2];
        out[b] = s + cb[0];                      // b == (t*75+q)*5 + w
    }
}

// ---------------------------------------------------------------------------
extern "C" void kernel_launch(void* const* d_in, const int* in_sizes, int n_in,
                              void* d_out, int out_size, void* d_ws, size_t ws_size,
                              hipStream_t stream) {
    const float* q   = (const float*)d_in[0];   // (8,75,64,21,21)
    const float* sup = (const float*)d_in[1];   // (8,25,64,21,21)
    const float* cw  = (const float*)d_in[2];   // (441,)
    const float* cb  = (const float*)d_in[3];   // (1,)
    float* out = (float*)d_out;                  // (8,75,5)

    float* wsf  = (float*)d_ws;
    float* Wbuf = wsf;                           // 163840 floats
    float* pG   = wsf + 163840;                  // 819200 floats
    float* pS   = wsf + 163840 + 819200;         // 12800 floats

    k_partial<<<TT * 25, 256, 0, stream>>>(sup, pG, pS);
    k_finalize<<<TT * WAY, 256, 0, stream>>>(pG, pS, Wbuf);
    k_sim<<<TT * WQ * WAY, 448, 0, stream>>>(q, Wbuf, cw, cb, out);
}